// Round 1
// baseline (780.162 us; speedup 1.0000x reference)
//
#include <hip/hip_runtime.h>
#include <math.h>

// Problem constants (also derived from in_sizes at launch)
#define NNODES 20000
#define NEDGES 640000

__device__ __forceinline__ float sspf(float x) {
    // softplus(x) - log(2); |x| <= ~8 in practice, no overflow concerns
    return __logf(1.0f + __expf(x)) - 0.6931471805599453f;
}

constexpr float INV_M      = 0.17677669529663687f;   // 1/sqrt(32)
constexpr float INV_R      = 0.25f;                  // 1/sqrt(16)
constexpr float INV_H      = 0.125f;                 // 1/sqrt(64)
constexpr float INV_2M_DEG = 0.125f * 0.17677669529663687f; // 1/sqrt(64) * 1/sqrt(32)
constexpr float INV_FAN    = 0.0625f;                // 1/sqrt(32*8)
constexpr float INV_SQRT3  = 0.5773502691896258f;

// ---------------- Kernel A: linear_1 (per-irrep channel mixing) ----------------
// s_ws[n][32] = node_s @ W1s / sqrt(32)
// v_ws[n][3][32] = einsum(node_v, W1v) / sqrt(32)   (component-major for coalesced edge gathers)
__global__ __launch_bounds__(256) void k_lin1(
    const float* __restrict__ node_s, const float* __restrict__ node_v,
    const float* __restrict__ W1s, const float* __restrict__ W1v,
    float* __restrict__ s_ws, float* __restrict__ v_ws, int N)
{
    __shared__ float sWs[1024], sWv[1024];
    for (int i = threadIdx.x; i < 1024; i += 256) {
        sWs[i] = W1s[i] * INV_M;
        sWv[i] = W1v[i] * INV_M;
    }
    __syncthreads();
    int j = threadIdx.x & 31;
    int n = blockIdx.x * 8 + (threadIdx.x >> 5);
    if (n >= N) return;
    const float* ss = node_s + (size_t)n * 32;
    const float* vv = node_v + (size_t)n * 96;
    float as = 0.f, a0 = 0.f, a1 = 0.f, a2 = 0.f;
    #pragma unroll
    for (int u = 0; u < 32; ++u) {
        float ws_ = sWs[u * 32 + j];
        float wv_ = sWv[u * 32 + j];
        as = fmaf(ss[u], ws_, as);
        a0 = fmaf(vv[u * 3 + 0], wv_, a0);
        a1 = fmaf(vv[u * 3 + 1], wv_, a1);
        a2 = fmaf(vv[u * 3 + 2], wv_, a2);
    }
    s_ws[(size_t)n * 32 + j] = as;
    v_ws[(size_t)n * 96 + j] = a0;
    v_ws[(size_t)n * 96 + 32 + j] = a1;
    v_ws[(size_t)n * 96 + 64 + j] = a2;
}

// ---------------- Kernel B: radial MLP + CG tensor product + atomic scatter ----------------
// One wave per edge. Lane j owns h[j], then w[j] (wa) and w[64+j] (wb).
// agg_s layout [N][64] (paths s0|s1), agg_v layout [N][3][64] (component-major, paths v0|v1).
__global__ __launch_bounds__(256) void k_edge(
    const float* __restrict__ edge_emb, const float* __restrict__ edge_y0,
    const float* __restrict__ edge_y1, const int* __restrict__ edge_index,
    const float* __restrict__ Wr1, const float* __restrict__ Wr2,
    const float* __restrict__ s_ws, const float* __restrict__ v_ws,
    float* __restrict__ agg_s, float* __restrict__ agg_v, int E)
{
    // Wr2 staged as interleaved pairs: pair p=(k*64+j) -> {Wr2[k][j], Wr2[k][j+64]} * 1/sqrt(64)
    __shared__ float sW2[8192];
    for (int p = threadIdx.x; p < 4096; p += 256) {
        int k = p >> 6, j = p & 63;
        sW2[2 * p]     = Wr2[k * 128 + j]      * INV_H;
        sW2[2 * p + 1] = Wr2[k * 128 + 64 + j] * INV_H;
    }
    __syncthreads();

    int lane = threadIdx.x & 63;
    // Per-lane Wr1 column in registers, 1/sqrt(16) folded
    float wr1[16];
    #pragma unroll
    for (int k = 0; k < 16; ++k) wr1[k] = Wr1[k * 64 + lane] * INV_R;

    const float2* w2p = (const float2*)sW2;
    int wid = (blockIdx.x * 256 + threadIdx.x) >> 6;
    int nw  = (gridDim.x * 256) >> 6;

    for (int e = wid; e < E; e += nw) {
        // --- radial MLP layer 1: h[lane] ---
        const float4* emb4 = (const float4*)(edge_emb + (size_t)e * 16);
        float4 q0 = emb4[0], q1 = emb4[1], q2 = emb4[2], q3 = emb4[3];
        float x;
        x = q0.x * wr1[0];
        x = fmaf(q0.y, wr1[1], x);  x = fmaf(q0.z, wr1[2], x);  x = fmaf(q0.w, wr1[3], x);
        x = fmaf(q1.x, wr1[4], x);  x = fmaf(q1.y, wr1[5], x);  x = fmaf(q1.z, wr1[6], x);
        x = fmaf(q1.w, wr1[7], x);  x = fmaf(q2.x, wr1[8], x);  x = fmaf(q2.y, wr1[9], x);
        x = fmaf(q2.z, wr1[10], x); x = fmaf(q2.w, wr1[11], x); x = fmaf(q3.x, wr1[12], x);
        x = fmaf(q3.y, wr1[13], x); x = fmaf(q3.z, wr1[14], x); x = fmaf(q3.w, wr1[15], x);
        float h = sspf(x);

        // --- radial MLP layer 2: wa = w[lane], wb = w[64+lane] ---
        float wa = 0.f, wb = 0.f;
        #pragma unroll
        for (int k = 0; k < 64; ++k) {
            float hk = __shfl(h, k, 64);
            float2 ww = w2p[k * 64 + lane];
            wa = fmaf(hk, ww.x, wa);
            wb = fmaf(hk, ww.y, wb);
        }

        // --- gather source features ---
        int src = edge_index[e];
        int dst = edge_index[E + e];
        int u = lane & 31;
        float y0e = edge_y0[e];
        float y1x = edge_y1[(size_t)e * 3];
        float y1y = edge_y1[(size_t)e * 3 + 1];
        float y1z = edge_y1[(size_t)e * 3 + 2];
        const float* sp = s_ws + (size_t)src * 32;
        const float* vp = v_ws + (size_t)src * 96;
        float se = sp[u];
        float vx = vp[u], vy = vp[32 + u], vz = vp[64 + u];
        float dot = vx * y1x + vy * y1y + vz * y1z;

        // Exchange halves: low lane j gets w2[j]; high lane 32+u gets w3[u]
        float wXa = __shfl_xor(wa, 32, 64);
        float wXb = __shfl_xor(wb, 32, 64);

        bool low = (lane < 32);
        // agg_s[dst][lane]: lane<32 -> w1*se*y0 ; lane>=32 -> w4*(ve.y1)/sqrt(3)
        float vs_ = low ? (wa * se * y0e) : (wb * dot * INV_SQRT3);
        // agg_v[dst][i][lane]: lane<32 -> w2*se*y1[i] ; lane>=32 -> w3*ve[i]*y0
        float c0, c1, c2;
        if (low) {
            float t = wXa * se;
            c0 = t * y1x; c1 = t * y1y; c2 = t * y1z;
        } else {
            float t = wXb * y0e;
            c0 = t * vx; c1 = t * vy; c2 = t * vz;
        }

        float* as_ = agg_s + (size_t)dst * 64 + lane;
        float* av_ = agg_v + (size_t)dst * 192 + lane;
        atomicAdd(as_, vs_);
        atomicAdd(av_, c0);
        atomicAdd(av_ + 64, c1);
        atomicAdd(av_ + 128, c2);
    }
}

// ---------------- Kernel C: linear_2 + self-connection + output assembly ----------------
__global__ __launch_bounds__(256) void k_out(
    const float* __restrict__ node_s, const float* __restrict__ node_v,
    const float* __restrict__ attrs,
    const float* __restrict__ agg_s, const float* __restrict__ agg_v,
    const float* __restrict__ W2s, const float* __restrict__ W2v,
    const float* __restrict__ Wscs, const float* __restrict__ Wscv,
    float* __restrict__ out, int N)
{
    __shared__ float sW2s[2048], sW2v[2048], sCs[8192], sCv[8192];
    for (int i = threadIdx.x; i < 2048; i += 256) {
        sW2s[i] = W2s[i] * INV_2M_DEG;   // fold 1/sqrt(64) * 1/sqrt(avg_neigh)
        sW2v[i] = W2v[i] * INV_2M_DEG;
    }
    for (int i = threadIdx.x; i < 8192; i += 256) {
        sCs[i] = Wscs[i] * INV_FAN;
        sCv[i] = Wscv[i] * INV_FAN;
    }
    __syncthreads();
    int j = threadIdx.x & 31;
    int n = blockIdx.x * 8 + (threadIdx.x >> 5);
    if (n >= N) return;

    float at[8];
    #pragma unroll
    for (int a = 0; a < 8; ++a) at[a] = attrs[(size_t)n * 8 + a];

    float os = 0.f, o0 = 0.f, o1 = 0.f, o2 = 0.f;
    const float* ags = agg_s + (size_t)n * 64;
    const float* agv = agg_v + (size_t)n * 192;
    #pragma unroll
    for (int u = 0; u < 64; ++u) {
        float w2s = sW2s[u * 32 + j];
        float w2v = sW2v[u * 32 + j];
        os = fmaf(ags[u], w2s, os);
        o0 = fmaf(agv[u], w2v, o0);
        o1 = fmaf(agv[64 + u], w2v, o1);
        o2 = fmaf(agv[128 + u], w2v, o2);
    }

    const float* sn = node_s + (size_t)n * 32;
    const float* vn = node_v + (size_t)n * 96;
    #pragma unroll 4
    for (int u = 0; u < 32; ++u) {
        float su = sn[u];
        float v0 = vn[u * 3], v1 = vn[u * 3 + 1], v2 = vn[u * 3 + 2];
        #pragma unroll
        for (int a = 0; a < 8; ++a) {
            float ca = at[a];
            float wcs = sCs[(u * 8 + a) * 32 + j];
            float wcv = sCv[(u * 8 + a) * 32 + j];
            os = fmaf(su * ca, wcs, os);
            float t = ca * wcv;
            o0 = fmaf(v0, t, o0);
            o1 = fmaf(v1, t, o1);
            o2 = fmaf(v2, t, o2);
        }
    }

    float* op = out + (size_t)n * 128;
    op[j] = os;
    op[32 + j * 3 + 0] = o0;
    op[32 + j * 3 + 1] = o1;
    op[32 + j * 3 + 2] = o2;
}

extern "C" void kernel_launch(void* const* d_in, const int* in_sizes, int n_in,
                              void* d_out, int out_size, void* d_ws, size_t ws_size,
                              hipStream_t stream)
{
    const float* node_s = (const float*)d_in[0];
    const float* node_v = (const float*)d_in[1];
    const float* attrs  = (const float*)d_in[2];
    const float* emb    = (const float*)d_in[3];
    const float* y0     = (const float*)d_in[4];
    const float* y1     = (const float*)d_in[5];
    const int*   eidx   = (const int*)d_in[6];
    const float* W1s  = (const float*)d_in[7];
    const float* W1v  = (const float*)d_in[8];
    const float* Wr1  = (const float*)d_in[9];
    const float* Wr2  = (const float*)d_in[10];
    const float* W2s  = (const float*)d_in[11];
    const float* W2v  = (const float*)d_in[12];
    const float* Wscs = (const float*)d_in[13];
    const float* Wscv = (const float*)d_in[14];

    int N = in_sizes[0] / 32;   // 20000
    int E = in_sizes[3] / 16;   // 640000

    float* ws    = (float*)d_ws;
    float* s_ws  = ws;                              // N*32
    float* v_ws  = s_ws + (size_t)N * 32;           // N*96  ([N][3][32])
    float* agg_s = v_ws + (size_t)N * 96;           // N*64
    float* agg_v = agg_s + (size_t)N * 64;          // N*192 ([N][3][64])

    // zero the aggregation buffers (ws is poisoned before every launch)
    hipMemsetAsync(agg_s, 0, (size_t)N * 256 * sizeof(float), stream);

    k_lin1<<<dim3((N + 7) / 8), dim3(256), 0, stream>>>(node_s, node_v, W1s, W1v, s_ws, v_ws, N);
    k_edge<<<dim3(2048), dim3(256), 0, stream>>>(emb, y0, y1, eidx, Wr1, Wr2, s_ws, v_ws, agg_s, agg_v, E);
    k_out<<<dim3((N + 7) / 8), dim3(256), 0, stream>>>(node_s, node_v, attrs, agg_s, agg_v,
                                                       W2s, W2v, Wscs, Wscv, (float*)d_out, N);
}